// Round 6
// baseline (13431.485 us; speedup 1.0000x reference)
//
#include <hip/hip_runtime.h>
#include <math.h>

#define HD   256
#define RB   4      // batch rows per block  (8 -> 4: grid 512 = 2 blocks/CU)
#define TB   256    // threads per block
#define TT   64     // time steps
#define NST  32     // ode steps
#define BSZ  2048

// ---------------- math helpers ----------------
__device__ __forceinline__ float sigmoidf_(float x) {
    return 1.0f / (1.0f + __expf(-x));
}
__device__ __forceinline__ float tanhf_(float x) {
    float e = __expf(2.0f * x);
    return 1.0f - 2.0f / (e + 1.0f);
}
__device__ __forceinline__ float seluf_(float x) {
    const float a = 1.6732632423543772f, s = 1.0507009873554805f;
    return x > 0.0f ? s * x : s * a * (__expf(x) - 1.0f);
}
// XLA f32 erf_inv (Giles polynomial)
__device__ __forceinline__ float erfinvf_(float x) {
    float w = -log1pf(-x * x);
    float p;
    if (w < 5.0f) {
        w -= 2.5f;
        p = 2.81022636e-08f;
        p = fmaf(p, w, 3.43273939e-07f);
        p = fmaf(p, w, -3.5233877e-06f);
        p = fmaf(p, w, -4.39150654e-06f);
        p = fmaf(p, w, 0.00021858087f);
        p = fmaf(p, w, -0.00125372503f);
        p = fmaf(p, w, -0.00417768164f);
        p = fmaf(p, w, 0.246640727f);
        p = fmaf(p, w, 1.50140941f);
    } else {
        w = sqrtf(w) - 3.0f;
        p = -0.000200214257f;
        p = fmaf(p, w, 0.000100950558f);
        p = fmaf(p, w, 0.00134934322f);
        p = fmaf(p, w, -0.00367342844f);
        p = fmaf(p, w, 0.00573950773f);
        p = fmaf(p, w, -0.0076224613f);
        p = fmaf(p, w, 0.00943887047f);
        p = fmaf(p, w, 1.00167406f);
        p = fmaf(p, w, 2.83297682f);
    }
    return p * x;
}

// ---------------- threefry2x32, key = (0, 42) ----------------
#define TF_ROUND(x0, x1, R) { x0 += x1; x1 = (x1 << (R)) | (x1 >> (32 - (R))); x1 ^= x0; }

__device__ __forceinline__ void threefry_(unsigned c0, unsigned c1, unsigned& r0, unsigned& r1) {
    const unsigned ks0 = 0u, ks1 = 42u, ks2 = 0x1BD11BDAu ^ 0u ^ 42u;
    unsigned x0 = c0 + ks0, x1 = c1 + ks1;
    TF_ROUND(x0,x1,13) TF_ROUND(x0,x1,15) TF_ROUND(x0,x1,26) TF_ROUND(x0,x1,6)
    x0 += ks1; x1 += ks2 + 1u;
    TF_ROUND(x0,x1,17) TF_ROUND(x0,x1,29) TF_ROUND(x0,x1,16) TF_ROUND(x0,x1,24)
    x0 += ks2; x1 += ks0 + 2u;
    TF_ROUND(x0,x1,13) TF_ROUND(x0,x1,15) TF_ROUND(x0,x1,26) TF_ROUND(x0,x1,6)
    x0 += ks0; x1 += ks1 + 3u;
    TF_ROUND(x0,x1,17) TF_ROUND(x0,x1,29) TF_ROUND(x0,x1,16) TF_ROUND(x0,x1,24)
    x0 += ks1; x1 += ks2 + 4u;
    TF_ROUND(x0,x1,13) TF_ROUND(x0,x1,15) TF_ROUND(x0,x1,26) TF_ROUND(x0,x1,6)
    x0 += ks2; x1 += ks0 + 5u;
    r0 = x0; r1 = x1;
}

// eps[i]: jax.random.normal(key(42), (2048,256), f32), jax_threefry_partitionable:
// bits = o0 ^ o1 of threefry2x32(key, (0, i))   [V4 -- verified round 5, absmax 0.0]
__device__ __forceinline__ float jax_normal_(unsigned i) {
    unsigned o0, o1;
    threefry_(0u, i, o0, o1);
    unsigned bits = o0 ^ o1;
    unsigned fb = (bits >> 9) | 0x3F800000u;
    float f = __uint_as_float(fb) - 1.0f;           // [0,1)
    const float lo = -0.99999994f;                  // nextafter(-1,0)
    float u = f * 2.0f + lo;
    u = fmaxf(lo, u);
    return 1.41421356237f * erfinvf_(u);
}

// ---------------- block-level 256->256 dense layer -> LDS ----------------
// thread tid owns output o = tid for all RB rows. ACT: 1 selu, 2 relu
template<int ACT>
__device__ __forceinline__ void layerD(const float (*in)[HD], float (*out)[HD],
                                       const float* __restrict__ W,
                                       const float* __restrict__ b, int tid) {
    const int o = tid;
    float acc[RB];
    const float bb = b[o];
#pragma unroll
    for (int r = 0; r < RB; ++r) acc[r] = bb;
    const float* wrow = W + (size_t)o * HD;
#pragma unroll 4
    for (int k0 = 0; k0 < HD; k0 += 4) {
        const float4 w = *(const float4*)(wrow + k0);
#pragma unroll
        for (int r = 0; r < RB; ++r) {
            const float4 iv = *(const float4*)(&in[r][k0]);
            acc[r] = fmaf(iv.w, w.w, fmaf(iv.z, w.z, fmaf(iv.y, w.y, fmaf(iv.x, w.x, acc[r]))));
        }
    }
#pragma unroll
    for (int r = 0; r < RB; ++r) {
        float v = acc[r];
        if (ACT == 1) v = seluf_(v);
        if (ACT == 2) v = fmaxf(v, 0.0f);
        out[r][o] = v;
    }
}

// ---------------- final layer -> registers (thread's own j only, no LDS, no sync) ----------------
__device__ __forceinline__ void layerD_reg(const float (*in)[HD], float (&kout)[RB],
                                           const float* __restrict__ W,
                                           const float* __restrict__ b, int tid) {
    const int o = tid;
    const float bb = b[o];
#pragma unroll
    for (int r = 0; r < RB; ++r) kout[r] = bb;
    const float* wrow = W + (size_t)o * HD;
#pragma unroll 4
    for (int k0 = 0; k0 < HD; k0 += 4) {
        const float4 w = *(const float4*)(wrow + k0);
#pragma unroll
        for (int r = 0; r < RB; ++r) {
            const float4 iv = *(const float4*)(&in[r][k0]);
            kout[r] = fmaf(iv.w, w.w, fmaf(iv.z, w.z, fmaf(iv.y, w.y, fmaf(iv.x, w.x, kout[r]))));
        }
    }
}

// ---------------- fused pipeline kernel ----------------
__global__ __launch_bounds__(TB) void fused_kernel(
    const float* __restrict__ x,      // [2048][64][4]
    const float* __restrict__ meta,   // [2048][4]
    const float* __restrict__ W_ih,   // [768][8]
    const float* __restrict__ W_hh,   // [768][256]
    const float* __restrict__ b_ih,   // [768]
    const float* __restrict__ b_hh,   // [768]
    const float* __restrict__ eW1,    // [256][256]
    const float* __restrict__ eb1,    // [256]
    const float* __restrict__ eW2,    // [512][256]
    const float* __restrict__ eb2,    // [512]
    const float* __restrict__ oW1, const float* __restrict__ ob1,
    const float* __restrict__ oW2, const float* __restrict__ ob2,
    const float* __restrict__ oW3, const float* __restrict__ ob3,
    const float* __restrict__ oW4, const float* __restrict__ ob4,
    const float* __restrict__ outW,   // [260]
    const float* __restrict__ outb,   // [1]
    float* __restrict__ out)          // [2048]
{
    const int tid = threadIdx.x;
    const int j = tid;
    const int b0 = blockIdx.x * RB;

    __shared__ float xall[RB][TT * 4];   // 4 KB
    __shared__ float meta_s[RB][4];
    __shared__ float h_s[RB][HD];        // 4 KB  (h, later y)
    __shared__ float tA[RB][HD];         // 4 KB
    __shared__ float tB[RB][HD];         // 4 KB
    __shared__ float ytmp[RB][HD];       // 4 KB
    __shared__ float dt_s[RB];
    __shared__ float red[TB];            // 1 KB
    // total ~21.3 KB -> LDS allows many blocks; grid 512 -> 2 blocks/CU

    // ---- stage x, meta; zero h ----
#pragma unroll
    for (int i = 0; i < RB; ++i) {
        int idx = tid + i * TB;          // 0..RB*256-1
        int r = idx >> 8, c = idx & 255;
        xall[r][c] = x[(size_t)(b0 + r) * 256 + c];
    }
    if (tid < RB * 4) { int r = tid >> 2, m = tid & 3; meta_s[r][m] = meta[(b0 + r) * 4 + m]; }
#pragma unroll
    for (int r = 0; r < RB; ++r) h_s[r][j] = 0.0f;
    __syncthreads();

    // ---- GRU: thread j owns hidden index j; gate rows j (r), j+256 (z), j+512 (n) ----
    float wir[8], wiz[8], win[8];
#pragma unroll
    for (int d = 0; d < 8; ++d) {
        wir[d] = W_ih[(size_t)j * 8 + d];
        wiz[d] = W_ih[(size_t)(j + 256) * 8 + d];
        win[d] = W_ih[(size_t)(j + 512) * 8 + d];
    }
    const float* wr_row = W_hh + (size_t)j * HD;
    const float* wz_row = W_hh + (size_t)(j + 256) * HD;
    const float* wn_row = W_hh + (size_t)(j + 512) * HD;

    float base_r[RB], base_z[RB], base_xn[RB];
    {
        const float bir = b_ih[j], biz = b_ih[j + 256], bin_ = b_ih[j + 512];
        const float bhr = b_hh[j], bhz = b_hh[j + 256];
#pragma unroll
        for (int r = 0; r < RB; ++r) {
            float sr = bir + bhr, sz = biz + bhz, sn = bin_;
#pragma unroll
            for (int m = 0; m < 4; ++m) {
                float mv = meta_s[r][m];
                sr = fmaf(mv, wir[4 + m], sr);
                sz = fmaf(mv, wiz[4 + m], sz);
                sn = fmaf(mv, win[4 + m], sn);
            }
            base_r[r] = sr; base_z[r] = sz; base_xn[r] = sn;
        }
    }
    const float bhn = b_hh[j + 512];

    for (int t = 0; t < TT; ++t) {
        float ar[RB], az[RB], axn[RB], ahn[RB];
#pragma unroll
        for (int r = 0; r < RB; ++r) { ar[r] = base_r[r]; az[r] = base_z[r]; axn[r] = base_xn[r]; ahn[r] = bhn; }
#pragma unroll
        for (int k = 0; k < 4; ++k) {
#pragma unroll
            for (int r = 0; r < RB; ++r) {
                float xv = xall[r][t * 4 + k];
                ar[r]  = fmaf(xv, wir[k], ar[r]);
                az[r]  = fmaf(xv, wiz[k], az[r]);
                axn[r] = fmaf(xv, win[k], axn[r]);
            }
        }
#pragma unroll 4
        for (int k0 = 0; k0 < HD; k0 += 4) {
            const float4 wr4 = *(const float4*)(wr_row + k0);
            const float4 wz4 = *(const float4*)(wz_row + k0);
            const float4 wn4 = *(const float4*)(wn_row + k0);
#pragma unroll
            for (int r = 0; r < RB; ++r) {
                const float4 hv = *(const float4*)(&h_s[r][k0]);
                ar[r]  = fmaf(hv.w, wr4.w, fmaf(hv.z, wr4.z, fmaf(hv.y, wr4.y, fmaf(hv.x, wr4.x, ar[r]))));
                az[r]  = fmaf(hv.w, wz4.w, fmaf(hv.z, wz4.z, fmaf(hv.y, wz4.y, fmaf(hv.x, wz4.x, az[r]))));
                ahn[r] = fmaf(hv.w, wn4.w, fmaf(hv.z, wn4.z, fmaf(hv.y, wn4.y, fmaf(hv.x, wn4.x, ahn[r]))));
            }
        }
        __syncthreads();
#pragma unroll
        for (int r = 0; r < RB; ++r) {
            float rg = sigmoidf_(ar[r]);
            float zg = sigmoidf_(az[r]);
            float ng = tanhf_(fmaf(rg, ahn[r], axn[r]));
            float hp = h_s[r][j];
            h_s[r][j] = fmaf(zg, hp - ng, ng);   // (1-z)*n + z*h
        }
        __syncthreads();
    }

    // ---- encoder: h1 = relu(h@eW1.T+eb1) -> tA ; mean/std rows j / j+256 of eW2 ----
    layerD<2>(h_s, tA, eW1, eb1, tid);
    __syncthreads();
    {
        float am[RB], as_[RB];
        const float bm = eb2[j], bs = eb2[j + 256];
#pragma unroll
        for (int r = 0; r < RB; ++r) { am[r] = bm; as_[r] = bs; }
        const float* wmrow = eW2 + (size_t)j * HD;
        const float* wsrow = eW2 + (size_t)(j + 256) * HD;
#pragma unroll 4
        for (int k0 = 0; k0 < HD; k0 += 4) {
            const float4 wm = *(const float4*)(wmrow + k0);
            const float4 ws4 = *(const float4*)(wsrow + k0);
#pragma unroll
            for (int r = 0; r < RB; ++r) {
                const float4 hv = *(const float4*)(&tA[r][k0]);
                am[r]  = fmaf(hv.w, wm.w, fmaf(hv.z, wm.z, fmaf(hv.y, wm.y, fmaf(hv.x, wm.x, am[r]))));
                as_[r] = fmaf(hv.w, ws4.w, fmaf(hv.z, ws4.z, fmaf(hv.y, ws4.y, fmaf(hv.x, ws4.x, as_[r]))));
            }
        }
#pragma unroll
        for (int r = 0; r < RB; ++r) {
            unsigned i = (unsigned)((b0 + r) * HD + j);
            float e = jax_normal_(i);
            h_s[r][j] = fmaf(e, as_[r], am[r]);   // y0 = eps*std + mean
        }
    }
    if (tid < RB) dt_s[tid] = (xall[tid][252] - xall[tid][0]) * (1.0f / 32.0f);
    __syncthreads();

    // ---- dopri5, 32 steps; k1..k6 live in REGISTERS (thread's own j) ----
    const float A21 = (float)(1.0/5.0);
    const float A31 = (float)(3.0/40.0),      A32 = (float)(9.0/40.0);
    const float A41 = (float)(44.0/45.0),     A42 = (float)(-56.0/15.0),    A43 = (float)(32.0/9.0);
    const float A51 = (float)(19372.0/6561.0),A52 = (float)(-25360.0/2187.0),
                A53 = (float)(64448.0/6561.0),A54 = (float)(-212.0/729.0);
    const float A61 = (float)(9017.0/3168.0), A62 = (float)(-355.0/33.0),
                A63 = (float)(46732.0/5247.0),A64 = (float)(49.0/176.0),    A65 = (float)(-5103.0/18656.0);
    const float B1f = (float)(35.0/384.0),    B3f = (float)(500.0/1113.0),  B4f = (float)(125.0/192.0),
                B5f = (float)(-2187.0/6784.0),B6f = (float)(11.0/84.0);

    float k1[RB], k2[RB], k3[RB], k4[RB], k5[RB], k6[RB];

    // ODE_EVAL: 3 LDS layers (sync each) + final layer into registers (no sync)
#define ODE_EVAL(YIN, KOUT)                                      \
    layerD<1>(YIN, tA, oW1, ob1, tid); __syncthreads();          \
    layerD<1>(tA,  tB, oW2, ob2, tid); __syncthreads();          \
    layerD<1>(tB,  tA, oW3, ob3, tid); __syncthreads();          \
    layerD_reg(tA, KOUT, oW4, ob4, tid);

    for (int st = 0; st < NST; ++st) {
        ODE_EVAL(h_s, k1)
#pragma unroll
        for (int r = 0; r < RB; ++r)
            ytmp[r][j] = fmaf(dt_s[r], A21 * k1[r], h_s[r][j]);
        __syncthreads();

        ODE_EVAL(ytmp, k2)
#pragma unroll
        for (int r = 0; r < RB; ++r) {
            float s = fmaf(A32, k2[r], A31 * k1[r]);
            ytmp[r][j] = fmaf(dt_s[r], s, h_s[r][j]);
        }
        __syncthreads();

        ODE_EVAL(ytmp, k3)
#pragma unroll
        for (int r = 0; r < RB; ++r) {
            float s = fmaf(A43, k3[r], fmaf(A42, k2[r], A41 * k1[r]));
            ytmp[r][j] = fmaf(dt_s[r], s, h_s[r][j]);
        }
        __syncthreads();

        ODE_EVAL(ytmp, k4)
#pragma unroll
        for (int r = 0; r < RB; ++r) {
            float s = fmaf(A54, k4[r], fmaf(A53, k3[r], fmaf(A52, k2[r], A51 * k1[r])));
            ytmp[r][j] = fmaf(dt_s[r], s, h_s[r][j]);
        }
        __syncthreads();

        ODE_EVAL(ytmp, k5)
#pragma unroll
        for (int r = 0; r < RB; ++r) {
            float s = fmaf(A65, k5[r], fmaf(A64, k4[r],
                      fmaf(A63, k3[r], fmaf(A62, k2[r], A61 * k1[r]))));
            ytmp[r][j] = fmaf(dt_s[r], s, h_s[r][j]);
        }
        __syncthreads();

        ODE_EVAL(ytmp, k6)
#pragma unroll
        for (int r = 0; r < RB; ++r) {
            float s = fmaf(B6f, k6[r], fmaf(B5f, k5[r],
                      fmaf(B4f, k4[r], fmaf(B3f, k3[r], B1f * k1[r]))));
            h_s[r][j] = fmaf(dt_s[r], s, h_s[r][j]);
        }
        __syncthreads();
    }
#undef ODE_EVAL

    // ---- output head ----
    const float wj = outW[j];
    for (int r = 0; r < RB; ++r) {
        red[tid] = h_s[r][j] * wj;
        __syncthreads();
        for (int s = 128; s > 0; s >>= 1) {
            if (tid < s) red[tid] += red[tid + s];
            __syncthreads();
        }
        if (tid == 0) {
            float acc = red[0] + outb[0];
#pragma unroll
            for (int m = 0; m < 4; ++m) acc = fmaf(meta_s[r][m], outW[HD + m], acc);
            out[b0 + r] = acc;
        }
        __syncthreads();
    }
}

extern "C" void kernel_launch(void* const* d_in, const int* in_sizes, int n_in,
                              void* d_out, int out_size, void* d_ws, size_t ws_size,
                              hipStream_t stream) {
    const float* x    = (const float*)d_in[0];
    const float* meta = (const float*)d_in[1];
    const float* W_ih = (const float*)d_in[2];
    const float* W_hh = (const float*)d_in[3];
    const float* b_ih = (const float*)d_in[4];
    const float* b_hh = (const float*)d_in[5];
    const float* eW1  = (const float*)d_in[6];
    const float* eb1  = (const float*)d_in[7];
    const float* eW2  = (const float*)d_in[8];
    const float* eb2  = (const float*)d_in[9];
    const float* oW1  = (const float*)d_in[10];
    const float* ob1  = (const float*)d_in[11];
    const float* oW2  = (const float*)d_in[12];
    const float* ob2  = (const float*)d_in[13];
    const float* oW3  = (const float*)d_in[14];
    const float* ob3  = (const float*)d_in[15];
    const float* oW4  = (const float*)d_in[16];
    const float* ob4  = (const float*)d_in[17];
    const float* outW = (const float*)d_in[18];
    const float* outb = (const float*)d_in[19];

    fused_kernel<<<BSZ / RB, TB, 0, stream>>>(x, meta, W_ih, W_hh, b_ih, b_hh,
                                              eW1, eb1, eW2, eb2,
                                              oW1, ob1, oW2, ob2, oW3, ob3, oW4, ob4,
                                              outW, outb, (float*)d_out);
}

// Round 8
// 12755.085 us; speedup vs baseline: 1.0530x; 1.0530x over previous
//
#include <hip/hip_runtime.h>
#include <math.h>

#define HD   256
#define RB   8      // batch rows per block -> grid 256
#define TB   512    // 8 waves: wave-half 0 = rows 0..3, half 1 = rows 4..7
#define RPT  4      // rows per thread
#define NT   8      // k-tiles per 256-k layer (KT = 32)
#define TT   64
#define NST  32
#define BSZ  2048

// ---------------- math helpers ----------------
__device__ __forceinline__ float sigmoidf_(float x) {
    return 1.0f / (1.0f + __expf(-x));
}
__device__ __forceinline__ float tanhf_(float x) {
    float e = __expf(2.0f * x);
    return 1.0f - 2.0f / (e + 1.0f);
}
__device__ __forceinline__ float seluf_(float x) {
    const float a = 1.6732632423543772f, s = 1.0507009873554805f;
    return x > 0.0f ? s * x : s * a * (__expf(x) - 1.0f);
}
__device__ __forceinline__ float erfinvf_(float x) {
    float w = -log1pf(-x * x);
    float p;
    if (w < 5.0f) {
        w -= 2.5f;
        p = 2.81022636e-08f;
        p = fmaf(p, w, 3.43273939e-07f);
        p = fmaf(p, w, -3.5233877e-06f);
        p = fmaf(p, w, -4.39150654e-06f);
        p = fmaf(p, w, 0.00021858087f);
        p = fmaf(p, w, -0.00125372503f);
        p = fmaf(p, w, -0.00417768164f);
        p = fmaf(p, w, 0.246640727f);
        p = fmaf(p, w, 1.50140941f);
    } else {
        w = sqrtf(w) - 3.0f;
        p = -0.000200214257f;
        p = fmaf(p, w, 0.000100950558f);
        p = fmaf(p, w, 0.00134934322f);
        p = fmaf(p, w, -0.00367342844f);
        p = fmaf(p, w, 0.00573950773f);
        p = fmaf(p, w, -0.0076224613f);
        p = fmaf(p, w, 0.00943887047f);
        p = fmaf(p, w, 1.00167406f);
        p = fmaf(p, w, 2.83297682f);
    }
    return p * x;
}

#define TF_ROUND(x0, x1, R) { x0 += x1; x1 = (x1 << (R)) | (x1 >> (32 - (R))); x1 ^= x0; }

__device__ __forceinline__ void threefry_(unsigned c0, unsigned c1, unsigned& r0, unsigned& r1) {
    const unsigned ks0 = 0u, ks1 = 42u, ks2 = 0x1BD11BDAu ^ 0u ^ 42u;
    unsigned x0 = c0 + ks0, x1 = c1 + ks1;
    TF_ROUND(x0,x1,13) TF_ROUND(x0,x1,15) TF_ROUND(x0,x1,26) TF_ROUND(x0,x1,6)
    x0 += ks1; x1 += ks2 + 1u;
    TF_ROUND(x0,x1,17) TF_ROUND(x0,x1,29) TF_ROUND(x0,x1,16) TF_ROUND(x0,x1,24)
    x0 += ks2; x1 += ks0 + 2u;
    TF_ROUND(x0,x1,13) TF_ROUND(x0,x1,15) TF_ROUND(x0,x1,26) TF_ROUND(x0,x1,6)
    x0 += ks0; x1 += ks1 + 3u;
    TF_ROUND(x0,x1,17) TF_ROUND(x0,x1,29) TF_ROUND(x0,x1,16) TF_ROUND(x0,x1,24)
    x0 += ks1; x1 += ks2 + 4u;
    TF_ROUND(x0,x1,13) TF_ROUND(x0,x1,15) TF_ROUND(x0,x1,26) TF_ROUND(x0,x1,6)
    x0 += ks2; x1 += ks0 + 5u;
    r0 = x0; r1 = x1;
}

// eps[i]: bits = o0 ^ o1 of threefry2x32(key(0,42), (0, i))  [verified round 5, absmax 0.0]
__device__ __forceinline__ float jax_normal_(unsigned i) {
    unsigned o0, o1;
    threefry_(0u, i, o0, o1);
    unsigned bits = o0 ^ o1;
    unsigned fb = (bits >> 9) | 0x3F800000u;
    float f = __uint_as_float(fb) - 1.0f;
    const float lo = -0.99999994f;
    float u = f * 2.0f + lo;
    u = fmaxf(lo, u);
    return 1.41421356237f * erfinvf_(u);
}

// ---------------- LDS-staged 256x256 dense apply ----------------
// W row-major [256 out][256 k] read DIRECTLY from global (coalesced tile staging),
// double-buffered KT=32 tiles in WL (XOR-swizzled to kill bank conflicts).
// Thread (j = tid&255, rbase = (tid>>8)*RPT) accumulates out[rbase..rbase+3][j] into acc.
// All 512 threads must call (uniform barriers).
__device__ __forceinline__ void applyA(const float4* __restrict__ Wf4,
                                       const float (*__restrict__ in)[HD],
                                       float4 (*__restrict__ WL)[2048],
                                       float (&acc)[RPT],
                                       const int j, const int rbase, const int tid)
{
#pragma unroll
    for (int r = 0; r < RPT; ++r) acc[r] = 0.0f;

    // per-thread staging constants: 4 float4s per tile
    const int f0 = tid, f1 = tid + TB, f2 = tid + 2*TB, f3 = tid + 3*TB;
    const int r0_ = f0 >> 3, r1_ = f1 >> 3, r2_ = f2 >> 3, r3_ = f3 >> 3;
    const int c0_ = f0 & 7,  c1_ = f1 & 7,  c2_ = f2 & 7,  c3_ = f3 & 7;
    const int go0 = r0_*64 + c0_, go1 = r1_*64 + c1_, go2 = r2_*64 + c2_, go3 = r3_*64 + c3_;
    const int li0 = (r0_<<3) | (c0_ ^ (r0_&7));
    const int li1 = (r1_<<3) | (c1_ ^ (r1_&7));
    const int li2 = (r2_<<3) | (c2_ ^ (r2_&7));
    const int li3 = (r3_<<3) | (c3_ ^ (r3_&7));
    const int wbase = j << 3;
    const int js = j & 7;

    float4 s0 = Wf4[go0], s1 = Wf4[go1], s2 = Wf4[go2], s3 = Wf4[go3];
    WL[0][li0] = s0; WL[0][li1] = s1; WL[0][li2] = s2; WL[0][li3] = s3;
    __syncthreads();

    int buf = 0;
#pragma unroll 1
    for (int t = 0; t < NT; ++t) {
        if (t < NT - 1) {
            const int k4 = (t + 1) * 8;
            s0 = Wf4[go0 + k4]; s1 = Wf4[go1 + k4]; s2 = Wf4[go2 + k4]; s3 = Wf4[go3 + k4];
        }
#pragma unroll
        for (int c4 = 0; c4 < 8; ++c4) {
            const float4 w = WL[buf][wbase | (c4 ^ js)];
#pragma unroll
            for (int r = 0; r < RPT; ++r) {
                const float4 a = *(const float4*)(&in[rbase + r][t*32 + c4*4]);
                acc[r] = fmaf(a.w, w.w, fmaf(a.z, w.z, fmaf(a.y, w.y, fmaf(a.x, w.x, acc[r]))));
            }
        }
        if (t < NT - 1) {
            WL[buf^1][li0] = s0; WL[buf^1][li1] = s1; WL[buf^1][li2] = s2; WL[buf^1][li3] = s3;
        }
        __syncthreads();
        buf ^= 1;
    }
}

// ---------------- fused pipeline kernel (no workspace at all) ----------------
__global__ __launch_bounds__(TB) void fused_kernel(
    const float* __restrict__ x,      // [2048][64][4]
    const float* __restrict__ meta,   // [2048][4]
    const float* __restrict__ W_ih,   // [768][8]
    const float* __restrict__ W_hh,   // [768][256]
    const float* __restrict__ b_ih,   // [768]
    const float* __restrict__ b_hh,   // [768]
    const float* __restrict__ eW1,    // [256][256]
    const float* __restrict__ eb1,    // [256]
    const float* __restrict__ eW2,    // [512][256]
    const float* __restrict__ eb2,    // [512]
    const float* __restrict__ oW1, const float* __restrict__ ob1,
    const float* __restrict__ oW2, const float* __restrict__ ob2,
    const float* __restrict__ oW3, const float* __restrict__ ob3,
    const float* __restrict__ oW4, const float* __restrict__ ob4,
    const float* __restrict__ outW,   // [260]
    const float* __restrict__ outb,   // [1]
    float* __restrict__ out)          // [2048]
{
    const int tid = threadIdx.x;
    const int j = tid & 255;
    const int rbase = (tid >> 8) * RPT;
    const int b0 = blockIdx.x * RB;

    __shared__ float4 WL[2][2048];       // 64 KB weight tiles (double-buffered)
    __shared__ float h_s[RB][HD];        // 8 KB (h, then y)
    __shared__ float tA[RB][HD];         // 8 KB
    __shared__ float tB[RB][HD];         // 8 KB
    __shared__ float ytmp[RB][HD];       // 8 KB
    __shared__ float xall[RB][TT * 4];   // 8 KB
    __shared__ float meta_s[RB][4];
    __shared__ float dt_s[RB];
    __shared__ float red[TB];            // 2 KB
    // total ~106 KB -> 1 block/CU, 8 waves = 2 waves/SIMD

    const float4* Whh4 = (const float4*)W_hh;   // gate blocks: +0 (r), +16384 (z), +32768 (n)
    const float4* E1f4 = (const float4*)eW1;
    const float4* E2f4 = (const float4*)eW2;    // mean rows 0..255; std = +16384
    const float4* O1f4 = (const float4*)oW1;
    const float4* O2f4 = (const float4*)oW2;
    const float4* O3f4 = (const float4*)oW3;
    const float4* O4f4 = (const float4*)oW4;

    typedef const float (*cmat)[HD];
    cmat h_sc = (cmat)h_s, tAc = (cmat)tA, tBc = (cmat)tB, ytc = (cmat)ytmp;

    // ---- stage x, meta; zero h ----
#pragma unroll
    for (int i = 0; i < 4; ++i) {
        int idx = tid + i * TB;          // 0..2047
        int r = idx >> 8, c = idx & 255;
        xall[r][c] = x[(size_t)(b0 + r) * 256 + c];
    }
    if (tid < RB * 4) { int r = tid >> 2, m = tid & 3; meta_s[r][m] = meta[(b0 + r) * 4 + m]; }
#pragma unroll
    for (int r = 0; r < RPT; ++r) h_s[rbase + r][j] = 0.0f;
    if (tid < RB) dt_s[tid] = 0.0f;   // set for real later
    __syncthreads();

    // ---- GRU x-side constants (per-thread gathers, once) ----
    float wir[8], wiz[8], win[8];
#pragma unroll
    for (int d = 0; d < 8; ++d) {
        wir[d] = W_ih[(size_t)j * 8 + d];
        wiz[d] = W_ih[(size_t)(j + 256) * 8 + d];
        win[d] = W_ih[(size_t)(j + 512) * 8 + d];
    }
    float base_r[RPT], base_z[RPT], base_xn[RPT];
    {
        const float bir = b_ih[j], biz = b_ih[j + 256], bin_ = b_ih[j + 512];
        const float bhr = b_hh[j], bhz = b_hh[j + 256];
#pragma unroll
        for (int r = 0; r < RPT; ++r) {
            const int R = rbase + r;
            float sr = bir + bhr, sz = biz + bhz, sn = bin_;
#pragma unroll
            for (int m = 0; m < 4; ++m) {
                float mv = meta_s[R][m];
                sr = fmaf(mv, wir[4 + m], sr);
                sz = fmaf(mv, wiz[4 + m], sz);
                sn = fmaf(mv, win[4 + m], sn);
            }
            base_r[r] = sr; base_z[r] = sz; base_xn[r] = sn;
        }
    }
    const float bhn = b_hh[512 + j];

    // ---- GRU: 64 steps, 3 LDS-staged gate matmuls per step ----
#pragma unroll 1
    for (int t = 0; t < TT; ++t) {
        float aR[RPT], aZ[RPT], aN[RPT];
        applyA(Whh4,         h_sc, WL, aR, j, rbase, tid);
        applyA(Whh4 + 16384, h_sc, WL, aZ, j, rbase, tid);
        applyA(Whh4 + 32768, h_sc, WL, aN, j, rbase, tid);
#pragma unroll
        for (int r = 0; r < RPT; ++r) {
            const int R = rbase + r;
            float xr = base_r[r], xz = base_z[r], xn = base_xn[r];
#pragma unroll
            for (int k = 0; k < 4; ++k) {
                float xv = xall[R][t * 4 + k];
                xr = fmaf(xv, wir[k], xr);
                xz = fmaf(xv, wiz[k], xz);
                xn = fmaf(xv, win[k], xn);
            }
            float rg = sigmoidf_(xr + aR[r]);
            float zg = sigmoidf_(xz + aZ[r]);
            float ng = tanhf_(fmaf(rg, bhn + aN[r], xn));
            float hp = h_s[R][j];
            h_s[R][j] = fmaf(zg, hp - ng, ng);   // (1-z)*n + z*h
        }
        // visibility of h_s covered by next applyA's prologue barrier
    }

    // ---- encoder ----
    {
        float aH[RPT];
        applyA(E1f4, h_sc, WL, aH, j, rbase, tid);
        const float eb1j = eb1[j];
#pragma unroll
        for (int r = 0; r < RPT; ++r) tA[rbase + r][j] = fmaxf(aH[r] + eb1j, 0.0f);

        float aM[RPT], aS[RPT];
        applyA(E2f4,         tAc, WL, aM, j, rbase, tid);
        applyA(E2f4 + 16384, tAc, WL, aS, j, rbase, tid);
        const float bm = eb2[j], bs = eb2[256 + j];
#pragma unroll
        for (int r = 0; r < RPT; ++r) {
            const int R = rbase + r;
            float e = jax_normal_((unsigned)((b0 + R) * HD + j));
            h_s[R][j] = fmaf(e, aS[r] + bs, aM[r] + bm);   // y0
        }
        if (tid < RB) dt_s[tid] = (xall[tid][TT * 4 - 4] - xall[tid][0]) * (1.0f / (float)NST);
    }

    // ---- dopri5 ----
    const float A21 = (float)(1.0/5.0);
    const float A31 = (float)(3.0/40.0),      A32 = (float)(9.0/40.0);
    const float A41 = (float)(44.0/45.0),     A42 = (float)(-56.0/15.0),    A43 = (float)(32.0/9.0);
    const float A51 = (float)(19372.0/6561.0),A52 = (float)(-25360.0/2187.0),
                A53 = (float)(64448.0/6561.0),A54 = (float)(-212.0/729.0);
    const float A61 = (float)(9017.0/3168.0), A62 = (float)(-355.0/33.0),
                A63 = (float)(46732.0/5247.0),A64 = (float)(49.0/176.0),    A65 = (float)(-5103.0/18656.0);
    const float B1f = (float)(35.0/384.0),    B3f = (float)(500.0/1113.0),  B4f = (float)(125.0/192.0),
                B5f = (float)(-2187.0/6784.0),B6f = (float)(11.0/84.0);

    const float ob1j = ob1[j], ob2j = ob2[j], ob3j = ob3[j], ob4j = ob4[j];
    float k1[RPT], k2[RPT], k3[RPT], k4[RPT], k5[RPT], k6[RPT];

#pragma unroll 1
    for (int st = 0; st < NST; ++st) {
#pragma unroll 1
        for (int s = 0; s < 6; ++s) {
            cmat yin = (s == 0) ? h_sc : ytc;
            float a4[RPT];
            applyA(O1f4, yin, WL, a4, j, rbase, tid);
#pragma unroll
            for (int r = 0; r < RPT; ++r) tA[rbase + r][j] = seluf_(a4[r] + ob1j);
            applyA(O2f4, tAc, WL, a4, j, rbase, tid);
#pragma unroll
            for (int r = 0; r < RPT; ++r) tB[rbase + r][j] = seluf_(a4[r] + ob2j);
            applyA(O3f4, tBc, WL, a4, j, rbase, tid);
#pragma unroll
            for (int r = 0; r < RPT; ++r) tA[rbase + r][j] = seluf_(a4[r] + ob3j);
            applyA(O4f4, tAc, WL, a4, j, rbase, tid);

            switch (s) {
            case 0:
#pragma unroll
                for (int r = 0; r < RPT; ++r) {
                    const int R = rbase + r;
                    k1[r] = a4[r] + ob4j;
                    ytmp[R][j] = fmaf(dt_s[R], A21 * k1[r], h_s[R][j]);
                } break;
            case 1:
#pragma unroll
                for (int r = 0; r < RPT; ++r) {
                    const int R = rbase + r;
                    k2[r] = a4[r] + ob4j;
                    float sm = fmaf(A32, k2[r], A31 * k1[r]);
                    ytmp[R][j] = fmaf(dt_s[R], sm, h_s[R][j]);
                } break;
            case 2:
#pragma unroll
                for (int r = 0; r < RPT; ++r) {
                    const int R = rbase + r;
                    k3[r] = a4[r] + ob4j;
                    float sm = fmaf(A43, k3[r], fmaf(A42, k2[r], A41 * k1[r]));
                    ytmp[R][j] = fmaf(dt_s[R], sm, h_s[R][j]);
                } break;
            case 3:
#pragma unroll
                for (int r = 0; r < RPT; ++r) {
                    const int R = rbase + r;
                    k4[r] = a4[r] + ob4j;
                    float sm = fmaf(A54, k4[r], fmaf(A53, k3[r], fmaf(A52, k2[r], A51 * k1[r])));
                    ytmp[R][j] = fmaf(dt_s[R], sm, h_s[R][j]);
                } break;
            case 4:
#pragma unroll
                for (int r = 0; r < RPT; ++r) {
                    const int R = rbase + r;
                    k5[r] = a4[r] + ob4j;
                    float sm = fmaf(A65, k5[r], fmaf(A64, k4[r],
                               fmaf(A63, k3[r], fmaf(A62, k2[r], A61 * k1[r]))));
                    ytmp[R][j] = fmaf(dt_s[R], sm, h_s[R][j]);
                } break;
            default:
#pragma unroll
                for (int r = 0; r < RPT; ++r) {
                    const int R = rbase + r;
                    k6[r] = a4[r] + ob4j;
                    float sm = fmaf(B6f, k6[r], fmaf(B5f, k5[r],
                               fmaf(B4f, k4[r], fmaf(B3f, k3[r], B1f * k1[r]))));
                    h_s[R][j] = fmaf(dt_s[R], sm, h_s[R][j]);
                } break;
            }
            // visibility covered by next applyA prologue barrier
        }
    }

    // ---- output head: two rows per reduction pass (halves of the 512 threads) ----
    __syncthreads();
#pragma unroll 1
    for (int rp = 0; rp < RB / 2; ++rp) {
        const int r0 = rp * 2;
        const int half = tid >> 8;           // 0 or 1
        const int jj = tid & 255;
        red[tid] = h_s[r0 + half][jj] * outW[jj];
        __syncthreads();
        for (int s = 128; s > 0; s >>= 1) {
            if ((tid & 255) < s) red[tid] += red[tid + s];
            __syncthreads();
        }
        if (jj == 0) {
            const int R = r0 + half;
            float acc = red[half << 8] + outb[0];
#pragma unroll
            for (int m = 0; m < 4; ++m) acc = fmaf(meta_s[R][m], outW[HD + m], acc);
            out[b0 + R] = acc;
        }
        __syncthreads();
    }
}

extern "C" void kernel_launch(void* const* d_in, const int* in_sizes, int n_in,
                              void* d_out, int out_size, void* d_ws, size_t ws_size,
                              hipStream_t stream) {
    const float* x    = (const float*)d_in[0];
    const float* meta = (const float*)d_in[1];
    const float* W_ih = (const float*)d_in[2];
    const float* W_hh = (const float*)d_in[3];
    const float* b_ih = (const float*)d_in[4];
    const float* b_hh = (const float*)d_in[5];
    const float* eW1  = (const float*)d_in[6];
    const float* eb1  = (const float*)d_in[7];
    const float* eW2  = (const float*)d_in[8];
    const float* eb2  = (const float*)d_in[9];
    const float* oW1  = (const float*)d_in[10];
    const float* ob1  = (const float*)d_in[11];
    const float* oW2  = (const float*)d_in[12];
    const float* ob2  = (const float*)d_in[13];
    const float* oW3  = (const float*)d_in[14];
    const float* ob3  = (const float*)d_in[15];
    const float* oW4  = (const float*)d_in[16];
    const float* ob4  = (const float*)d_in[17];
    const float* outW = (const float*)d_in[18];
    const float* outb = (const float*)d_in[19];

    fused_kernel<<<BSZ / RB, TB, 0, stream>>>(x, meta, W_ih, W_hh, b_ih, b_hh,
                                              eW1, eb1, eW2, eb2,
                                              oW1, ob1, oW2, ob2, oW3, ob3, oW4, ob4,
                                              outW, outb, (float*)d_out);
}

// Round 9
// 6183.818 us; speedup vs baseline: 2.1720x; 2.0627x over previous
//
#include <hip/hip_runtime.h>
#include <math.h>

#define HD   256
#define RB   8      // batch rows per block -> grid 256 = 1 block/CU
#define TB   512    // 8 waves; half 0 = rows 0..3, half 1 = rows 4..7
#define RPH  4      // rows per half
#define TT   64
#define NST  32
#define BSZ  2048

// ---------------- math helpers ----------------
__device__ __forceinline__ float sigmoidf_(float x) {
    return 1.0f / (1.0f + __expf(-x));
}
__device__ __forceinline__ float tanhf_(float x) {
    float e = __expf(2.0f * x);
    return 1.0f - 2.0f / (e + 1.0f);
}
__device__ __forceinline__ float seluf_(float x) {
    const float a = 1.6732632423543772f, s = 1.0507009873554805f;
    return x > 0.0f ? s * x : s * a * (__expf(x) - 1.0f);
}
__device__ __forceinline__ float erfinvf_(float x) {
    float w = -log1pf(-x * x);
    float p;
    if (w < 5.0f) {
        w -= 2.5f;
        p = 2.81022636e-08f;
        p = fmaf(p, w, 3.43273939e-07f);
        p = fmaf(p, w, -3.5233877e-06f);
        p = fmaf(p, w, -4.39150654e-06f);
        p = fmaf(p, w, 0.00021858087f);
        p = fmaf(p, w, -0.00125372503f);
        p = fmaf(p, w, -0.00417768164f);
        p = fmaf(p, w, 0.246640727f);
        p = fmaf(p, w, 1.50140941f);
    } else {
        w = sqrtf(w) - 3.0f;
        p = -0.000200214257f;
        p = fmaf(p, w, 0.000100950558f);
        p = fmaf(p, w, 0.00134934322f);
        p = fmaf(p, w, -0.00367342844f);
        p = fmaf(p, w, 0.00573950773f);
        p = fmaf(p, w, -0.0076224613f);
        p = fmaf(p, w, 0.00943887047f);
        p = fmaf(p, w, 1.00167406f);
        p = fmaf(p, w, 2.83297682f);
    }
    return p * x;
}

#define TF_ROUND(x0, x1, R) { x0 += x1; x1 = (x1 << (R)) | (x1 >> (32 - (R))); x1 ^= x0; }

__device__ __forceinline__ void threefry_(unsigned c0, unsigned c1, unsigned& r0, unsigned& r1) {
    const unsigned ks0 = 0u, ks1 = 42u, ks2 = 0x1BD11BDAu ^ 0u ^ 42u;
    unsigned x0 = c0 + ks0, x1 = c1 + ks1;
    TF_ROUND(x0,x1,13) TF_ROUND(x0,x1,15) TF_ROUND(x0,x1,26) TF_ROUND(x0,x1,6)
    x0 += ks1; x1 += ks2 + 1u;
    TF_ROUND(x0,x1,17) TF_ROUND(x0,x1,29) TF_ROUND(x0,x1,16) TF_ROUND(x0,x1,24)
    x0 += ks2; x1 += ks0 + 2u;
    TF_ROUND(x0,x1,13) TF_ROUND(x0,x1,15) TF_ROUND(x0,x1,26) TF_ROUND(x0,x1,6)
    x0 += ks0; x1 += ks1 + 3u;
    TF_ROUND(x0,x1,17) TF_ROUND(x0,x1,29) TF_ROUND(x0,x1,16) TF_ROUND(x0,x1,24)
    x0 += ks1; x1 += ks2 + 4u;
    TF_ROUND(x0,x1,13) TF_ROUND(x0,x1,15) TF_ROUND(x0,x1,26) TF_ROUND(x0,x1,6)
    x0 += ks2; x1 += ks0 + 5u;
    r0 = x0; r1 = x1;
}

// eps[i]: bits = o0 ^ o1 of threefry2x32(key(0,42), (0, i))  [verified round 5]
__device__ __forceinline__ float jax_normal_(unsigned i) {
    unsigned o0, o1;
    threefry_(0u, i, o0, o1);
    unsigned bits = o0 ^ o1;
    unsigned fb = (bits >> 9) | 0x3F800000u;
    float f = __uint_as_float(fb) - 1.0f;
    const float lo = -0.99999994f;
    float u = f * 2.0f + lo;
    u = fmaxf(lo, u);
    return 1.41421356237f * erfinvf_(u);
}

// ---------------- quad-cooperative 256x256 matmul ----------------
// W row-major [256+ out][256 k] viewed as float4 [out][64]. Quad lanes s=0..3 read
// 4 consecutive float4s (64B, one cache line) of each output row -> 16 transactions
// per load instr (vs 64 for per-lane rows). Each thread accumulates quarter-sums for
// outputs {oj, oj+64, oj+128, oj+192} x RPH rows; 2-step quad butterfly restores the
// full k-sum; lane keeps m == s, i.e. output jj = oj + 64*s.
__device__ __forceinline__ void quadmm(const float4* __restrict__ W4,
                                       const float (*__restrict__ in)[HD],
                                       float (&res)[RPH],
                                       const int oj, const int s, const int rbase)
{
    float a0[RPH], a1[RPH], a2[RPH], a3[RPH];
#pragma unroll
    for (int r = 0; r < RPH; ++r) { a0[r] = 0.f; a1[r] = 0.f; a2[r] = 0.f; a3[r] = 0.f; }
    const float4* wp = W4 + oj * 64 + s;
#pragma unroll 4
    for (int g = 0; g < 16; ++g) {
        const int ko = g * 16 + s * 4;
        const float4 w0 = wp[g * 4];
        const float4 w1 = wp[g * 4 + 64 * 64];
        const float4 w2 = wp[g * 4 + 128 * 64];
        const float4 w3 = wp[g * 4 + 192 * 64];
#pragma unroll
        for (int r = 0; r < RPH; ++r) {
            const float4 av = *(const float4*)(&in[rbase + r][ko]);
            a0[r] = fmaf(av.w, w0.w, fmaf(av.z, w0.z, fmaf(av.y, w0.y, fmaf(av.x, w0.x, a0[r]))));
            a1[r] = fmaf(av.w, w1.w, fmaf(av.z, w1.z, fmaf(av.y, w1.y, fmaf(av.x, w1.x, a1[r]))));
            a2[r] = fmaf(av.w, w2.w, fmaf(av.z, w2.z, fmaf(av.y, w2.y, fmaf(av.x, w2.x, a2[r]))));
            a3[r] = fmaf(av.w, w3.w, fmaf(av.z, w3.z, fmaf(av.y, w3.y, fmaf(av.x, w3.x, a3[r]))));
        }
    }
#pragma unroll
    for (int r = 0; r < RPH; ++r) {
        float v0 = a0[r]; v0 += __shfl_xor(v0, 1); v0 += __shfl_xor(v0, 2);
        float v1 = a1[r]; v1 += __shfl_xor(v1, 1); v1 += __shfl_xor(v1, 2);
        float v2 = a2[r]; v2 += __shfl_xor(v2, 1); v2 += __shfl_xor(v2, 2);
        float v3 = a3[r]; v3 += __shfl_xor(v3, 1); v3 += __shfl_xor(v3, 2);
        res[r] = (s == 0) ? v0 : (s == 1) ? v1 : (s == 2) ? v2 : v3;
    }
}

// ---------------- fused pipeline kernel ----------------
__global__ __launch_bounds__(TB, 2) void fused_kernel(
    const float* __restrict__ x,      // [2048][64][4]
    const float* __restrict__ meta,   // [2048][4]
    const float* __restrict__ W_ih,   // [768][8]
    const float* __restrict__ W_hh,   // [768][256]
    const float* __restrict__ b_ih,   // [768]
    const float* __restrict__ b_hh,   // [768]
    const float* __restrict__ eW1,    // [256][256]
    const float* __restrict__ eb1,    // [256]
    const float* __restrict__ eW2,    // [512][256]
    const float* __restrict__ eb2,    // [512]
    const float* __restrict__ oW1, const float* __restrict__ ob1,
    const float* __restrict__ oW2, const float* __restrict__ ob2,
    const float* __restrict__ oW3, const float* __restrict__ ob3,
    const float* __restrict__ oW4, const float* __restrict__ ob4,
    const float* __restrict__ outW,   // [260]
    const float* __restrict__ outb,   // [1]
    float* __restrict__ out)          // [2048]
{
    const int tid  = threadIdx.x;
    const int half = tid >> 8;           // 0: rows 0-3, 1: rows 4-7
    const int t8   = tid & 255;
    const int oj   = t8 >> 2;            // 0..63
    const int s    = t8 & 3;             // k-quarter / output-group select
    const int jj   = oj + 64 * s;        // output this lane finalizes (bijective in t8)
    const int rbase = half * RPH;
    const int b0 = blockIdx.x * RB;

    __shared__ float h0[RB][HD];         // h ping / y
    __shared__ float h1[RB][HD];         // h pong
    __shared__ float tA[RB][HD];
    __shared__ float tB[RB][HD];
    __shared__ float ytmp[RB][HD];
    __shared__ float xall[RB][TT * 4];
    __shared__ float meta_s[RB][4];
    __shared__ float dt_s[RB];
    __shared__ float red[TB];
    // ~52 KB LDS

    const float4* Whh4 = (const float4*)W_hh;   // gates: +0 (r), +16384 (z), +32768 (n)
    const float4* E1f4 = (const float4*)eW1;
    const float4* E2f4 = (const float4*)eW2;    // mean rows 0..255, std rows 256..511
    const float4* O1f4 = (const float4*)oW1;
    const float4* O2f4 = (const float4*)oW2;
    const float4* O3f4 = (const float4*)oW3;
    const float4* O4f4 = (const float4*)oW4;

    typedef const float (*cmat)[HD];
    cmat tAc = (cmat)tA, tBc = (cmat)tB, ytc = (cmat)ytmp;

    // ---- stage x, meta; zero h0 ----
#pragma unroll
    for (int i = 0; i < 4; ++i) {
        int idx = tid + i * TB;          // 0..2047
        int r = idx >> 8, c = idx & 255;
        xall[r][c] = x[(size_t)(b0 + r) * 256 + c];
    }
    if (tid < RB * 4) { int r = tid >> 2, m = tid & 3; meta_s[r][m] = meta[(b0 + r) * 4 + m]; }
#pragma unroll
    for (int r = 0; r < RPH; ++r) h0[rbase + r][jj] = 0.0f;
    __syncthreads();
    if (tid < RB) dt_s[tid] = (xall[tid][TT * 4 - 4] - xall[tid][0]) * (1.0f / (float)NST);

    // ---- GRU per-lane x-side constants for output jj ----
    float wir[4], wiz[4], win[4];
#pragma unroll
    for (int d = 0; d < 4; ++d) {
        wir[d] = W_ih[(size_t)jj * 8 + d];
        wiz[d] = W_ih[(size_t)(jj + 256) * 8 + d];
        win[d] = W_ih[(size_t)(jj + 512) * 8 + d];
    }
    float base_r[RPH], base_z[RPH], base_xn[RPH];
    {
        float mwr[4], mwz[4], mwn[4];
#pragma unroll
        for (int m = 0; m < 4; ++m) {
            mwr[m] = W_ih[(size_t)jj * 8 + 4 + m];
            mwz[m] = W_ih[(size_t)(jj + 256) * 8 + 4 + m];
            mwn[m] = W_ih[(size_t)(jj + 512) * 8 + 4 + m];
        }
        const float bir = b_ih[jj], biz = b_ih[jj + 256], bin_ = b_ih[jj + 512];
        const float bhr = b_hh[jj], bhz = b_hh[jj + 256];
#pragma unroll
        for (int r = 0; r < RPH; ++r) {
            const int R = rbase + r;
            float sr = bir + bhr, sz = biz + bhz, sn = bin_;
#pragma unroll
            for (int m = 0; m < 4; ++m) {
                float mv = meta_s[R][m];
                sr = fmaf(mv, mwr[m], sr);
                sz = fmaf(mv, mwz[m], sz);
                sn = fmaf(mv, mwn[m], sn);
            }
            base_r[r] = sr; base_z[r] = sz; base_xn[r] = sn;
        }
    }
    const float bhn = b_hh[512 + jj];

    // ---- GRU: 64 steps, ping-pong h0/h1, 1 barrier per step ----
    float (*hc)[HD] = h0;
    float (*hn)[HD] = h1;
#pragma unroll 1
    for (int t = 0; t < TT; ++t) {
        float aR[RPH], aZ[RPH], aN[RPH];
        quadmm(Whh4,         (cmat)hc, aR, oj, s, rbase);
        quadmm(Whh4 + 16384, (cmat)hc, aZ, oj, s, rbase);
        quadmm(Whh4 + 32768, (cmat)hc, aN, oj, s, rbase);
#pragma unroll
        for (int r = 0; r < RPH; ++r) {
            const int R = rbase + r;
            float xr = base_r[r], xz = base_z[r], xn = base_xn[r];
#pragma unroll
            for (int d = 0; d < 4; ++d) {
                float xv = xall[R][t * 4 + d];
                xr = fmaf(xv, wir[d], xr);
                xz = fmaf(xv, wiz[d], xz);
                xn = fmaf(xv, win[d], xn);
            }
            float rg = sigmoidf_(xr + aR[r]);
            float zg = sigmoidf_(xz + aZ[r]);
            float ng = tanhf_(fmaf(rg, bhn + aN[r], xn));
            float hp = hc[R][jj];
            hn[R][jj] = fmaf(zg, hp - ng, ng);   // (1-z)*n + z*h
        }
        __syncthreads();
        float (*tmp)[HD] = hc; hc = hn; hn = tmp;
    }
    // final h in h0 (64 swaps)

    // ---- encoder + sample y0 into h0 ----
    {
        float a[RPH];
        quadmm(E1f4, (cmat)h0, a, oj, s, rbase);
        const float eb1j = eb1[jj];
#pragma unroll
        for (int r = 0; r < RPH; ++r) tA[rbase + r][jj] = fmaxf(a[r] + eb1j, 0.0f);
        __syncthreads();

        float aM[RPH], aS[RPH];
        quadmm(E2f4,             tAc, aM, oj, s, rbase);
        quadmm(E2f4 + 256 * 64,  tAc, aS, oj, s, rbase);
        const float bm = eb2[jj], bs = eb2[256 + jj];
#pragma unroll
        for (int r = 0; r < RPH; ++r) {
            const int R = rbase + r;
            float e = jax_normal_((unsigned)((b0 + R) * HD + jj));
            h0[R][jj] = fmaf(e, aS[r] + bs, aM[r] + bm);   // y0
        }
        __syncthreads();
    }

    // ---- dopri5 ----
    const float A21 = (float)(1.0/5.0);
    const float A31 = (float)(3.0/40.0),      A32 = (float)(9.0/40.0);
    const float A41 = (float)(44.0/45.0),     A42 = (float)(-56.0/15.0),    A43 = (float)(32.0/9.0);
    const float A51 = (float)(19372.0/6561.0),A52 = (float)(-25360.0/2187.0),
                A53 = (float)(64448.0/6561.0),A54 = (float)(-212.0/729.0);
    const float A61 = (float)(9017.0/3168.0), A62 = (float)(-355.0/33.0),
                A63 = (float)(46732.0/5247.0),A64 = (float)(49.0/176.0),    A65 = (float)(-5103.0/18656.0);
    const float B1f = (float)(35.0/384.0),    B3f = (float)(500.0/1113.0),  B4f = (float)(125.0/192.0),
                B5f = (float)(-2187.0/6784.0),B6f = (float)(11.0/84.0);

    const float ob1j = ob1[jj], ob2j = ob2[jj], ob3j = ob3[jj], ob4j = ob4[jj];
    float k1[RPH], k2[RPH], k3[RPH], k4[RPH], k5[RPH], k6[RPH];

#pragma unroll 1
    for (int st = 0; st < NST; ++st) {
#pragma unroll 1
        for (int stage = 0; stage < 6; ++stage) {
            cmat yin = (stage == 0) ? (cmat)h0 : ytc;
            float a[RPH];
            quadmm(O1f4, yin, a, oj, s, rbase);
#pragma unroll
            for (int r = 0; r < RPH; ++r) tA[rbase + r][jj] = seluf_(a[r] + ob1j);
            __syncthreads();
            quadmm(O2f4, tAc, a, oj, s, rbase);
#pragma unroll
            for (int r = 0; r < RPH; ++r) tB[rbase + r][jj] = seluf_(a[r] + ob2j);
            __syncthreads();
            quadmm(O3f4, tBc, a, oj, s, rbase);
#pragma unroll
            for (int r = 0; r < RPH; ++r) tA[rbase + r][jj] = seluf_(a[r] + ob3j);
            __syncthreads();
            quadmm(O4f4, tAc, a, oj, s, rbase);

            switch (stage) {
            case 0:
#pragma unroll
                for (int r = 0; r < RPH; ++r) {
                    const int R = rbase + r;
                    k1[r] = a[r] + ob4j;
                    ytmp[R][jj] = fmaf(dt_s[R], A21 * k1[r], h0[R][jj]);
                } break;
            case 1:
#pragma unroll
                for (int r = 0; r < RPH; ++r) {
                    const int R = rbase + r;
                    k2[r] = a[r] + ob4j;
                    float sm = fmaf(A32, k2[r], A31 * k1[r]);
                    ytmp[R][jj] = fmaf(dt_s[R], sm, h0[R][jj]);
                } break;
            case 2:
#pragma unroll
                for (int r = 0; r < RPH; ++r) {
                    const int R = rbase + r;
                    k3[r] = a[r] + ob4j;
                    float sm = fmaf(A43, k3[r], fmaf(A42, k2[r], A41 * k1[r]));
                    ytmp[R][jj] = fmaf(dt_s[R], sm, h0[R][jj]);
                } break;
            case 3:
#pragma unroll
                for (int r = 0; r < RPH; ++r) {
                    const int R = rbase + r;
                    k4[r] = a[r] + ob4j;
                    float sm = fmaf(A54, k4[r], fmaf(A53, k3[r], fmaf(A52, k2[r], A51 * k1[r])));
                    ytmp[R][jj] = fmaf(dt_s[R], sm, h0[R][jj]);
                } break;
            case 4:
#pragma unroll
                for (int r = 0; r < RPH; ++r) {
                    const int R = rbase + r;
                    k5[r] = a[r] + ob4j;
                    float sm = fmaf(A65, k5[r], fmaf(A64, k4[r],
                               fmaf(A63, k3[r], fmaf(A62, k2[r], A61 * k1[r]))));
                    ytmp[R][jj] = fmaf(dt_s[R], sm, h0[R][jj]);
                } break;
            default:
#pragma unroll
                for (int r = 0; r < RPH; ++r) {
                    const int R = rbase + r;
                    k6[r] = a[r] + ob4j;
                    float sm = fmaf(B6f, k6[r], fmaf(B5f, k5[r],
                               fmaf(B4f, k4[r], fmaf(B3f, k3[r], B1f * k1[r]))));
                    h0[R][jj] = fmaf(dt_s[R], sm, h0[R][jj]);
                } break;
            }
            __syncthreads();
        }
    }

    // ---- output head: two rows per pass (one per half) ----
#pragma unroll 1
    for (int rp = 0; rp < RB / 2; ++rp) {
        const int r0 = rp * 2;
        const int jj8 = tid & 255;
        red[tid] = h0[r0 + half][jj8] * outW[jj8];
        __syncthreads();
        for (int sw = 128; sw > 0; sw >>= 1) {
            if ((tid & 255) < sw) red[tid] += red[tid + sw];
            __syncthreads();
        }
        if (jj8 == 0) {
            const int R = r0 + half;
            float acc = red[half << 8] + outb[0];
#pragma unroll
            for (int m = 0; m < 4; ++m) acc = fmaf(meta_s[R][m], outW[HD + m], acc);
            out[b0 + R] = acc;
        }
        __syncthreads();
    }
}

extern "C" void kernel_launch(void* const* d_in, const int* in_sizes, int n_in,
                              void* d_out, int out_size, void* d_ws, size_t ws_size,
                              hipStream_t stream) {
    const float* x    = (const float*)d_in[0];
    const float* meta = (const float*)d_in[1];
    const float* W_ih = (const float*)d_in[2];
    const float* W_hh = (const float*)d_in[3];
    const float* b_ih = (const float*)d_in[4];
    const float* b_hh = (const float*)d_in[5];
    const float* eW1  = (const float*)d_in[6];
    const float* eb1  = (const float*)d_in[7];
    const float* eW2  = (const float*)d_in[8];
    const float* eb2  = (const float*)d_in[9];
    const float* oW1  = (const float*)d_in[10];
    const float* ob1  = (const float*)d_in[11];
    const float* oW2  = (const float*)d_in[12];
    const float* ob2  = (const float*)d_in[13];
    const float* oW3  = (const float*)d_in[14];
    const float* ob3  = (const float*)d_in[15];
    const float* oW4  = (const float*)d_in[16];
    const float* ob4  = (const float*)d_in[17];
    const float* outW = (const float*)d_in[18];
    const float* outb = (const float*)d_in[19];

    fused_kernel<<<BSZ / RB, TB, 0, stream>>>(x, meta, W_ih, W_hh, b_ih, b_hh,
                                              eW1, eb1, eW2, eb2,
                                              oW1, ob1, oW2, ob2, oW3, ob3, oW4, ob4,
                                              outW, outb, (float*)d_out);
}

// Round 10
// 5769.486 us; speedup vs baseline: 2.3280x; 1.0718x over previous
//
#include <hip/hip_runtime.h>
#include <math.h>

#define HD   256
#define RB   8      // batch rows per block -> grid 256 = 1 block/CU
#define TB   512    // 8 waves; kh = tid>>8 selects k-half; epilogue rows kh*4..kh*4+3
#define RPH  4      // rows per half (epilogue ownership)
#define TT   64
#define NST  32
#define BSZ  2048

// ---------------- math helpers ----------------
__device__ __forceinline__ float sigmoidf_(float x) {
    return 1.0f / (1.0f + __expf(-x));
}
__device__ __forceinline__ float tanhf_(float x) {
    float e = __expf(2.0f * x);
    return 1.0f - 2.0f / (e + 1.0f);
}
__device__ __forceinline__ float seluf_(float x) {
    const float a = 1.6732632423543772f, s = 1.0507009873554805f;
    return x > 0.0f ? s * x : s * a * (__expf(x) - 1.0f);
}
__device__ __forceinline__ float erfinvf_(float x) {
    float w = -log1pf(-x * x);
    float p;
    if (w < 5.0f) {
        w -= 2.5f;
        p = 2.81022636e-08f;
        p = fmaf(p, w, 3.43273939e-07f);
        p = fmaf(p, w, -3.5233877e-06f);
        p = fmaf(p, w, -4.39150654e-06f);
        p = fmaf(p, w, 0.00021858087f);
        p = fmaf(p, w, -0.00125372503f);
        p = fmaf(p, w, -0.00417768164f);
        p = fmaf(p, w, 0.246640727f);
        p = fmaf(p, w, 1.50140941f);
    } else {
        w = sqrtf(w) - 3.0f;
        p = -0.000200214257f;
        p = fmaf(p, w, 0.000100950558f);
        p = fmaf(p, w, 0.00134934322f);
        p = fmaf(p, w, -0.00367342844f);
        p = fmaf(p, w, 0.00573950773f);
        p = fmaf(p, w, -0.0076224613f);
        p = fmaf(p, w, 0.00943887047f);
        p = fmaf(p, w, 1.00167406f);
        p = fmaf(p, w, 2.83297682f);
    }
    return p * x;
}

#define TF_ROUND(x0, x1, R) { x0 += x1; x1 = (x1 << (R)) | (x1 >> (32 - (R))); x1 ^= x0; }

__device__ __forceinline__ void threefry_(unsigned c0, unsigned c1, unsigned& r0, unsigned& r1) {
    const unsigned ks0 = 0u, ks1 = 42u, ks2 = 0x1BD11BDAu ^ 0u ^ 42u;
    unsigned x0 = c0 + ks0, x1 = c1 + ks1;
    TF_ROUND(x0,x1,13) TF_ROUND(x0,x1,15) TF_ROUND(x0,x1,26) TF_ROUND(x0,x1,6)
    x0 += ks1; x1 += ks2 + 1u;
    TF_ROUND(x0,x1,17) TF_ROUND(x0,x1,29) TF_ROUND(x0,x1,16) TF_ROUND(x0,x1,24)
    x0 += ks2; x1 += ks0 + 2u;
    TF_ROUND(x0,x1,13) TF_ROUND(x0,x1,15) TF_ROUND(x0,x1,26) TF_ROUND(x0,x1,6)
    x0 += ks0; x1 += ks1 + 3u;
    TF_ROUND(x0,x1,17) TF_ROUND(x0,x1,29) TF_ROUND(x0,x1,16) TF_ROUND(x0,x1,24)
    x0 += ks1; x1 += ks2 + 4u;
    TF_ROUND(x0,x1,13) TF_ROUND(x0,x1,15) TF_ROUND(x0,x1,26) TF_ROUND(x0,x1,6)
    x0 += ks2; x1 += ks0 + 5u;
    r0 = x0; r1 = x1;
}

// eps[i]: bits = o0 ^ o1 of threefry2x32(key(0,42), (0, i))  [verified round 5]
__device__ __forceinline__ float jax_normal_(unsigned i) {
    unsigned o0, o1;
    threefry_(0u, i, o0, o1);
    unsigned bits = o0 ^ o1;
    unsigned fb = (bits >> 9) | 0x3F800000u;
    float f = __uint_as_float(fb) - 1.0f;
    const float lo = -0.99999994f;
    float u = f * 2.0f + lo;
    u = fmaxf(lo, u);
    return 1.41421356237f * erfinvf_(u);
}

typedef const float (*cmat)[HD];

// ---------------- quad-cooperative, k-split 256x256 matmul ----------------
// W [256+ out][256 k] row-major as float4 [out][64]. Thread (kh=tid>>8, t8=tid&255):
// oj=t8>>2, s=t8&3, output jj = oj+64*s. Accumulates ALL 8 rows over its k-half
// (ko = kh*128 + g*16 + s*4, g=0..7): each W element is read exactly ONCE per block
// (halves the L2 traffic vs round 9). Quad butterfly reduces s; cross-half partials
// combine via LDS part[pb][kh][r][t8] (lane-linear -> conflict-free), one barrier,
// double-buffered pb so no second barrier is needed.
// Returns res[r] = full-k dot for rows kh*4+r (the half's epilogue rows).
__device__ __forceinline__ void quadmm(const float4* __restrict__ W4,
                                       cmat in,
                                       float (&res)[RPH],
                                       const int oj, const int s, const int kh,
                                       const int t8,
                                       float (*__restrict__ part)[2][RPH][256],
                                       const int pb)
{
    float acc0[RB], acc1[RB], acc2[RB], acc3[RB];
#pragma unroll
    for (int r = 0; r < RB; ++r) { acc0[r] = 0.f; acc1[r] = 0.f; acc2[r] = 0.f; acc3[r] = 0.f; }

    const float4* wp = W4 + oj * 64 + kh * 32 + s;
    const int kbase = kh * 128 + s * 4;
#pragma unroll 2
    for (int g = 0; g < 8; ++g) {
        const int ko = kbase + g * 16;
        const float4 w0 = wp[g * 4];
        const float4 w1 = wp[g * 4 + 64 * 64];
        const float4 w2 = wp[g * 4 + 128 * 64];
        const float4 w3 = wp[g * 4 + 192 * 64];
#pragma unroll
        for (int r = 0; r < RB; ++r) {
            const float4 av = *(const float4*)(&in[r][ko]);
            acc0[r] = fmaf(av.w, w0.w, fmaf(av.z, w0.z, fmaf(av.y, w0.y, fmaf(av.x, w0.x, acc0[r]))));
            acc1[r] = fmaf(av.w, w1.w, fmaf(av.z, w1.z, fmaf(av.y, w1.y, fmaf(av.x, w1.x, acc1[r]))));
            acc2[r] = fmaf(av.w, w2.w, fmaf(av.z, w2.z, fmaf(av.y, w2.y, fmaf(av.x, w2.x, acc2[r]))));
            acc3[r] = fmaf(av.w, w3.w, fmaf(av.z, w3.z, fmaf(av.y, w3.y, fmaf(av.x, w3.x, acc3[r]))));
        }
    }
    // butterfly over quad (k-chunks within this half); lane keeps group m == s
    float mine[RB];
#pragma unroll
    for (int r = 0; r < RB; ++r) {
        float v0 = acc0[r]; v0 += __shfl_xor(v0, 1); v0 += __shfl_xor(v0, 2);
        float v1 = acc1[r]; v1 += __shfl_xor(v1, 1); v1 += __shfl_xor(v1, 2);
        float v2 = acc2[r]; v2 += __shfl_xor(v2, 1); v2 += __shfl_xor(v2, 2);
        float v3 = acc3[r]; v3 += __shfl_xor(v3, 1); v3 += __shfl_xor(v3, 2);
        mine[r] = (s == 0) ? v0 : (s == 1) ? v1 : (s == 2) ? v2 : v3;
    }
    // cross-half combine (static indexing only; kh select via cndmask on values)
    float wv[RPH], ov[RPH];
#pragma unroll
    for (int r = 0; r < RPH; ++r) {
        wv[r] = (kh == 0) ? mine[RPH + r] : mine[r];   // rows the OTHER half finalizes
        ov[r] = (kh == 0) ? mine[r] : mine[RPH + r];   // rows WE finalize
    }
#pragma unroll
    for (int r = 0; r < RPH; ++r) part[pb][kh][r][t8] = wv[r];
    __syncthreads();
#pragma unroll
    for (int r = 0; r < RPH; ++r) res[r] = ov[r] + part[pb][kh ^ 1][r][t8];
}

// ---------------- fused pipeline kernel ----------------
__global__ __launch_bounds__(TB, 2) void fused_kernel(
    const float* __restrict__ x,      // [2048][64][4]
    const float* __restrict__ meta,   // [2048][4]
    const float* __restrict__ W_ih,   // [768][8]
    const float* __restrict__ W_hh,   // [768][256]
    const float* __restrict__ b_ih,   // [768]
    const float* __restrict__ b_hh,   // [768]
    const float* __restrict__ eW1,    // [256][256]
    const float* __restrict__ eb1,    // [256]
    const float* __restrict__ eW2,    // [512][256]
    const float* __restrict__ eb2,    // [512]
    const float* __restrict__ oW1, const float* __restrict__ ob1,
    const float* __restrict__ oW2, const float* __restrict__ ob2,
    const float* __restrict__ oW3, const float* __restrict__ ob3,
    const float* __restrict__ oW4, const float* __restrict__ ob4,
    const float* __restrict__ outW,   // [260]
    const float* __restrict__ outb,   // [1]
    float* __restrict__ out)          // [2048]
{
    const int tid  = threadIdx.x;
    const int kh   = tid >> 8;           // k-half; also epilogue row-half
    const int t8   = tid & 255;
    const int oj   = t8 >> 2;            // 0..63
    const int s    = t8 & 3;
    const int jj   = oj + 64 * s;        // output this lane finalizes
    const int rbase = kh * RPH;
    const int b0 = blockIdx.x * RB;

    __shared__ float h0[RB][HD];
    __shared__ float h1[RB][HD];
    __shared__ float tA[RB][HD];
    __shared__ float tB[RB][HD];
    __shared__ float ytmp[RB][HD];
    __shared__ float xall[RB][TT * 4];
    __shared__ float part[2][2][RPH][256];   // 16 KB partial-sum exchange
    __shared__ float meta_s[RB][4];
    __shared__ float dt_s[RB];
    __shared__ float red[TB];
    // ~68 KB LDS

    const float4* Whh4 = (const float4*)W_hh;
    const float4* E1f4 = (const float4*)eW1;
    const float4* E2f4 = (const float4*)eW2;
    const float4* O1f4 = (const float4*)oW1;
    const float4* O2f4 = (const float4*)oW2;
    const float4* O3f4 = (const float4*)oW3;
    const float4* O4f4 = (const float4*)oW4;

    cmat tAc = (cmat)tA, tBc = (cmat)tB, ytc = (cmat)ytmp;

    int pb = 0;
    auto QMM = [&](const float4* W4p, cmat inp, float (&r)[RPH]) {
        quadmm(W4p, inp, r, oj, s, kh, t8, part, pb);
        pb ^= 1;
    };

    // ---- stage x, meta; zero h0 ----
#pragma unroll
    for (int i = 0; i < 4; ++i) {
        int idx = tid + i * TB;
        int r = idx >> 8, c = idx & 255;
        xall[r][c] = x[(size_t)(b0 + r) * 256 + c];
    }
    if (tid < RB * 4) { int r = tid >> 2, m = tid & 3; meta_s[r][m] = meta[(b0 + r) * 4 + m]; }
#pragma unroll
    for (int r = 0; r < RPH; ++r) h0[rbase + r][jj] = 0.0f;
    __syncthreads();
    if (tid < RB) dt_s[tid] = (xall[tid][TT * 4 - 4] - xall[tid][0]) * (1.0f / (float)NST);

    // ---- GRU per-lane x-side constants for output jj ----
    float wir[4], wiz[4], win[4];
#pragma unroll
    for (int d = 0; d < 4; ++d) {
        wir[d] = W_ih[(size_t)jj * 8 + d];
        wiz[d] = W_ih[(size_t)(jj + 256) * 8 + d];
        win[d] = W_ih[(size_t)(jj + 512) * 8 + d];
    }
    float base_r[RPH], base_z[RPH], base_xn[RPH];
    {
        float mwr[4], mwz[4], mwn[4];
#pragma unroll
        for (int m = 0; m < 4; ++m) {
            mwr[m] = W_ih[(size_t)jj * 8 + 4 + m];
            mwz[m] = W_ih[(size_t)(jj + 256) * 8 + 4 + m];
            mwn[m] = W_ih[(size_t)(jj + 512) * 8 + 4 + m];
        }
        const float bir = b_ih[jj], biz = b_ih[jj + 256], bin_ = b_ih[jj + 512];
        const float bhr = b_hh[jj], bhz = b_hh[jj + 256];
#pragma unroll
        for (int r = 0; r < RPH; ++r) {
            const int R = rbase + r;
            float sr = bir + bhr, sz = biz + bhz, sn = bin_;
#pragma unroll
            for (int m = 0; m < 4; ++m) {
                float mv = meta_s[R][m];
                sr = fmaf(mv, mwr[m], sr);
                sz = fmaf(mv, mwz[m], sz);
                sn = fmaf(mv, mwn[m], sn);
            }
            base_r[r] = sr; base_z[r] = sz; base_xn[r] = sn;
        }
    }
    const float bhn = b_hh[512 + jj];

    // ---- GRU: 64 steps, ping-pong h0/h1 ----
    float (*hc)[HD] = h0;
    float (*hn)[HD] = h1;
#pragma unroll 1
    for (int t = 0; t < TT; ++t) {
        float aR[RPH], aZ[RPH], aN[RPH];
        QMM(Whh4,         (cmat)hc, aR);
        QMM(Whh4 + 16384, (cmat)hc, aZ);
        QMM(Whh4 + 32768, (cmat)hc, aN);
#pragma unroll
        for (int r = 0; r < RPH; ++r) {
            const int R = rbase + r;
            float xr = base_r[r], xz = base_z[r], xn = base_xn[r];
#pragma unroll
            for (int d = 0; d < 4; ++d) {
                float xv = xall[R][t * 4 + d];
                xr = fmaf(xv, wir[d], xr);
                xz = fmaf(xv, wiz[d], xz);
                xn = fmaf(xv, win[d], xn);
            }
            float rg = sigmoidf_(xr + aR[r]);
            float zg = sigmoidf_(xz + aZ[r]);
            float ng = tanhf_(fmaf(rg, bhn + aN[r], xn));
            float hp = hc[R][jj];
            hn[R][jj] = fmaf(zg, hp - ng, ng);
        }
        __syncthreads();
        float (*tmp)[HD] = hc; hc = hn; hn = tmp;
    }
    // final h in h0 (even number of swaps)

    // ---- encoder + sample y0 into h0 ----
    {
        float a[RPH];
        QMM(E1f4, (cmat)h0, a);
        const float eb1j = eb1[jj];
#pragma unroll
        for (int r = 0; r < RPH; ++r) tA[rbase + r][jj] = fmaxf(a[r] + eb1j, 0.0f);
        __syncthreads();

        float aM[RPH], aS[RPH];
        QMM(E2f4,            tAc, aM);
        QMM(E2f4 + 256 * 64, tAc, aS);
        const float bm = eb2[jj], bs = eb2[256 + jj];
#pragma unroll
        for (int r = 0; r < RPH; ++r) {
            const int R = rbase + r;
            float e = jax_normal_((unsigned)((b0 + R) * HD + jj));
            h0[R][jj] = fmaf(e, aS[r] + bs, aM[r] + bm);
        }
        __syncthreads();
    }

    // ---- dopri5 ----
    const float A21 = (float)(1.0/5.0);
    const float A31 = (float)(3.0/40.0),      A32 = (float)(9.0/40.0);
    const float A41 = (float)(44.0/45.0),     A42 = (float)(-56.0/15.0),    A43 = (float)(32.0/9.0);
    const float A51 = (float)(19372.0/6561.0),A52 = (float)(-25360.0/2187.0),
                A53 = (float)(64448.0/6561.0),A54 = (float)(-212.0/729.0);
    const float A61 = (float)(9017.0/3168.0), A62 = (float)(-355.0/33.0),
                A63 = (float)(46732.0/5247.0),A64 = (float)(49.0/176.0),    A65 = (float)(-5103.0/18656.0);
    const float B1f = (float)(35.0/384.0),    B3f = (float)(500.0/1113.0),  B4f = (float)(125.0/192.0),
                B5f = (float)(-2187.0/6784.0),B6f = (float)(11.0/84.0);

    const float ob1j = ob1[jj], ob2j = ob2[jj], ob3j = ob3[jj], ob4j = ob4[jj];
    float k1[RPH], k2[RPH], k3[RPH], k4[RPH], k5[RPH], k6[RPH];

#pragma unroll 1
    for (int st = 0; st < NST; ++st) {
#pragma unroll 1
        for (int stage = 0; stage < 6; ++stage) {
            cmat yin = (stage == 0) ? (cmat)h0 : ytc;
            float a[RPH];
            QMM(O1f4, yin, a);
#pragma unroll
            for (int r = 0; r < RPH; ++r) tA[rbase + r][jj] = seluf_(a[r] + ob1j);
            __syncthreads();
            QMM(O2f4, tAc, a);
#pragma unroll
            for (int r = 0; r < RPH; ++r) tB[rbase + r][jj] = seluf_(a[r] + ob2j);
            __syncthreads();
            QMM(O3f4, tBc, a);
#pragma unroll
            for (int r = 0; r < RPH; ++r) tA[rbase + r][jj] = seluf_(a[r] + ob3j);
            __syncthreads();
            QMM(O4f4, tAc, a);

            switch (stage) {
            case 0:
#pragma unroll
                for (int r = 0; r < RPH; ++r) {
                    const int R = rbase + r;
                    k1[r] = a[r] + ob4j;
                    ytmp[R][jj] = fmaf(dt_s[R], A21 * k1[r], h0[R][jj]);
                } break;
            case 1:
#pragma unroll
                for (int r = 0; r < RPH; ++r) {
                    const int R = rbase + r;
                    k2[r] = a[r] + ob4j;
                    float sm = fmaf(A32, k2[r], A31 * k1[r]);
                    ytmp[R][jj] = fmaf(dt_s[R], sm, h0[R][jj]);
                } break;
            case 2:
#pragma unroll
                for (int r = 0; r < RPH; ++r) {
                    const int R = rbase + r;
                    k3[r] = a[r] + ob4j;
                    float sm = fmaf(A43, k3[r], fmaf(A42, k2[r], A41 * k1[r]));
                    ytmp[R][jj] = fmaf(dt_s[R], sm, h0[R][jj]);
                } break;
            case 3:
#pragma unroll
                for (int r = 0; r < RPH; ++r) {
                    const int R = rbase + r;
                    k4[r] = a[r] + ob4j;
                    float sm = fmaf(A54, k4[r], fmaf(A53, k3[r], fmaf(A52, k2[r], A51 * k1[r])));
                    ytmp[R][jj] = fmaf(dt_s[R], sm, h0[R][jj]);
                } break;
            case 4:
#pragma unroll
                for (int r = 0; r < RPH; ++r) {
                    const int R = rbase + r;
                    k5[r] = a[r] + ob4j;
                    float sm = fmaf(A65, k5[r], fmaf(A64, k4[r],
                               fmaf(A63, k3[r], fmaf(A62, k2[r], A61 * k1[r]))));
                    ytmp[R][jj] = fmaf(dt_s[R], sm, h0[R][jj]);
                } break;
            default:
#pragma unroll
                for (int r = 0; r < RPH; ++r) {
                    const int R = rbase + r;
                    k6[r] = a[r] + ob4j;
                    float sm = fmaf(B6f, k6[r], fmaf(B5f, k5[r],
                               fmaf(B4f, k4[r], fmaf(B3f, k3[r], B1f * k1[r]))));
                    h0[R][jj] = fmaf(dt_s[R], sm, h0[R][jj]);
                } break;
            }
            __syncthreads();
        }
    }

    // ---- output head ----
#pragma unroll 1
    for (int rp = 0; rp < RB / 2; ++rp) {
        const int r0 = rp * 2;
        red[tid] = h0[r0 + kh][t8] * outW[t8];
        __syncthreads();
        for (int sw = 128; sw > 0; sw >>= 1) {
            if (t8 < sw) red[tid] += red[tid + sw];
            __syncthreads();
        }
        if (t8 == 0) {
            const int R = r0 + kh;
            float acc = red[kh << 8] + outb[0];
#pragma unroll
            for (int m = 0; m < 4; ++m) acc = fmaf(meta_s[R][m], outW[HD + m], acc);
            out[b0 + R] = acc;
        }
        __syncthreads();
    }
}

extern "C" void kernel_launch(void* const* d_in, const int* in_sizes, int n_in,
                              void* d_out, int out_size, void* d_ws, size_t ws_size,
                              hipStream_t stream) {
    const float* x    = (const float*)d_in[0];
    const float* meta = (const float*)d_in[1];
    const float* W_ih = (const float*)d_in[2];
    const float* W_hh = (const float*)d_in[3];
    const float* b_ih = (const float*)d_in[4];
    const float* b_hh = (const float*)d_in[5];
    const float* eW1  = (const float*)d_in[6];
    const float* eb1  = (const float*)d_in[7];
    const float* eW2  = (const float*)d_in[8];
    const float* eb2  = (const float*)d_in[9];
    const float* oW1  = (const float*)d_in[10];
    const float* ob1  = (const float*)d_in[11];
    const float* oW2  = (const float*)d_in[12];
    const float* ob2  = (const float*)d_in[13];
    const float* oW3  = (const float*)d_in[14];
    const float* ob3  = (const float*)d_in[15];
    const float* oW4  = (const float*)d_in[16];
    const float* ob4  = (const float*)d_in[17];
    const float* outW = (const float*)d_in[18];
    const float* outb = (const float*)d_in[19];

    fused_kernel<<<BSZ / RB, TB, 0, stream>>>(x, meta, W_ih, W_hh, b_ih, b_hh,
                                              eW1, eb1, eW2, eb2,
                                              oW1, ob1, oW2, ob2, oW3, ob3, oW4, ob4,
                                              outW, outb, (float*)d_out);
}